// Round 6
// baseline (788.881 us; speedup 1.0000x reference)
//
#include <hip/hip_runtime.h>
#include <hip/hip_fp16.h>

#define N_NODES 50000
#define N_EDGES 1600000
#define T_STEPS 50
#define DT      0.02f
#define NB      256    // buckets
#define NPB     196    // nodes per bucket (196*256 >= 50000)
#define CAP     6912   // max raw edges per bucket (mean 6272, +8 sigma)
#define CAP2    7168   // fixed padded slots per bucket (CAP + NPB, rounded)
#define TILE    4096   // edges per bucket_kernel block
#define G       8      // lanes per node group in step kernel

// ---------------- setup ----------------

__global__ __launch_bounds__(256) void zero_kernel(int* __restrict__ bucket_count) {
    bucket_count[threadIdx.x] = 0;
}

// ---------------- bucketing: staged, line-friendly appends ----------------
// u64 item: low 32 = record (src | fp16w<<16), high 32 = target-within-bucket
__global__ __launch_bounds__(256) void bucket_kernel(
    const int* __restrict__ src, const int* __restrict__ tgt,
    const float* __restrict__ sign, const float* __restrict__ syn_count,
    const float* __restrict__ syn_strength,
    int* __restrict__ bucket_count, unsigned long long* __restrict__ rec_buf)
{
    __shared__ int hist[NB], base_s[NB], cur[NB];
    int tid = threadIdx.x;
    hist[tid] = 0;
    __syncthreads();

    int e0 = blockIdx.x * TILE + tid;
    int bkt[16];
    unsigned long long item[16];
#pragma unroll
    for (int k = 0; k < 16; ++k) {
        int e = e0 + k * 256;
        if (e < N_EDGES) {
            int t = tgt[e];
            int b = t / NPB;
            int tl = t - b * NPB;
            float w = sign[e] * fmaxf(syn_count[e], 0.f) * fmaxf(syn_strength[e], 0.f);
            unsigned int rec = (unsigned int)src[e] |
                               ((unsigned int)__half_as_ushort(__float2half(w)) << 16);
            bkt[k] = b;
            item[k] = (unsigned long long)rec | ((unsigned long long)tl << 32);
            atomicAdd(&hist[b], 1);
        } else {
            bkt[k] = -1;
        }
    }
    __syncthreads();
    base_s[tid] = atomicAdd(&bucket_count[tid], hist[tid]);
    cur[tid] = 0;
    __syncthreads();
#pragma unroll
    for (int k = 0; k < 16; ++k) {
        if (bkt[k] >= 0) {
            int p = base_s[bkt[k]] + atomicAdd(&cur[bkt[k]], 1);
            if (p < CAP) rec_buf[(size_t)bkt[k] * CAP + p] = item[k];
        }
    }
}

// ---------------- per-bucket counting sort -> padded CSR + node init ----------------
// Pads each node's run to EVEN length with zero-records (src=0,w=0 no-ops) so
// the step kernel can do aligned uint2 pair-loads. Fixed CAP2 slots per bucket.
__global__ __launch_bounds__(256) void sort_kernel(
    const int* __restrict__ bucket_count,
    const unsigned long long* __restrict__ rec_buf,
    const float* __restrict__ bias, const float* __restrict__ time_const,
    unsigned int* __restrict__ edges_g,
    int* __restrict__ offsets, int* __restrict__ ends,
    float2* __restrict__ ab, float* __restrict__ v /* [4][N] SoA */,
    uint2* __restrict__ rates0 /* half4 per node */)
{
    __shared__ unsigned int sorted[CAP2];         // 28.7 KB
    __shared__ int loc_off[NPB + 1];
    __shared__ int loc_cnt[NPB];
    __shared__ int loc_cur[NPB];

    int b = blockIdx.x;
    int tid = threadIdx.x;
    int node_base = b * NPB;
    int n_nodes = min(NPB, N_NODES - node_base);
    int ebase = b * CAP2;
    int cnt = min(bucket_count[b], CAP);

    for (int i = tid; i < CAP2; i += 256) sorted[i] = 0;
    if (tid < NPB) loc_cnt[tid] = 0;
    __syncthreads();

    // pass 1: histogram by local target
    for (int i = tid; i < cnt; i += 256) {
        unsigned long long it = rec_buf[(size_t)b * CAP + i];
        atomicAdd(&loc_cnt[(int)(it >> 32)], 1);
    }
    __syncthreads();
    if (tid == 0) {
        int r = 0;
        for (int n = 0; n < n_nodes; ++n) {
            loc_off[n] = r;
            r += (loc_cnt[n] + 1) & ~1;   // pad to even
        }
        loc_off[n_nodes] = r;
    }
    __syncthreads();
    if (tid < n_nodes) loc_cur[tid] = loc_off[tid];
    __syncthreads();

    // pass 2: place (rec_buf re-read is L2-hot); pads stay 0
    for (int i = tid; i < cnt; i += 256) {
        unsigned long long it = rec_buf[(size_t)b * CAP + i];
        int p = atomicAdd(&loc_cur[(int)(it >> 32)], 1);
        sorted[p] = (unsigned int)it;
    }
    __syncthreads();

    // coalesced CSR write + per-node offsets/ends + node init (folded)
    int total = loc_off[n_nodes];
    for (int i = tid; i < total; i += 256) edges_g[ebase + i] = sorted[i];
    for (int n = tid; n < n_nodes; n += 256) {
        int gn = node_base + n;
        offsets[gn] = ebase + loc_off[n];
        ends[gn]    = ebase + loc_off[n + 1];
        float bb  = bias[gn];
        float tau = fmaxf(time_const[gn], DT);
        ab[gn] = make_float2(DT / tau, bb);
        v[gn] = bb; v[N_NODES + gn] = bb;
        v[2 * N_NODES + gn] = bb; v[3 * N_NODES + gn] = bb;
        __half hr = __float2half(fmaxf(bb, 0.f));
        __half2 h2 = __halves2half2(hr, hr);
        uint2 r0; r0.x = *(unsigned int*)&h2; r0.y = r0.x;
        rates0[gn] = r0;
    }
}

// ---------------- per-step fused gather + Euler update ----------------
__device__ __forceinline__ float rec_w(unsigned int rec) {
    return __half2float(__ushort_as_half((unsigned short)(rec >> 16)));
}
__device__ __forceinline__ float4 h4_to_f4(uint2 g) {
    __half2 h01 = *(__half2*)&g.x;
    __half2 h23 = *(__half2*)&g.y;
    float2 f01 = __half22float2(h01);
    float2 f23 = __half22float2(h23);
    return make_float4(f01.x, f01.y, f23.x, f23.y);
}

__global__ __launch_bounds__(256) void step_kernel(
    const uint2* __restrict__ rates_in /* half4/node */,
    __half* __restrict__ rates_out /* 4 halves/node */,
    float* __restrict__ v /* [4][N] SoA */,
    const float2* __restrict__ ab,
    const int* __restrict__ offsets, const int* __restrict__ ends,
    const unsigned int* __restrict__ edges,
    const float* __restrict__ x, float* __restrict__ out, int t, int nblk)
{
    // XCD-contiguous bijective swizzle
    int nb8 = nblk / 8;
    int idx = blockIdx.x;
    int node_block = (idx < nb8 * 8) ? (idx % 8) * nb8 + idx / 8 : idx;
    int node = node_block * (256 / G) + ((int)threadIdx.x / G);
    int lane = threadIdx.x & (G - 1);
    if (node >= N_NODES) return;

    int beg = offsets[node], end = ends[node];   // both even; run padded even
    float4 acc = make_float4(0.f, 0.f, 0.f, 0.f);

    // pair-loads (2 records per uint2), 2 pairs in flight, stride 2G records
    const uint2 zz = make_uint2(0u, 0u);
    int i = beg + 2 * lane;
    uint2 p0 = (i          < end) ? *(const uint2*)(edges + i)          : zz;
    uint2 p1 = (i + 2 * G  < end) ? *(const uint2*)(edges + i + 2 * G)  : zz;
    while (i < end) {
        uint2 q0 = (i + 4 * G < end) ? *(const uint2*)(edges + i + 4 * G) : zz;
        uint2 q1 = (i + 6 * G < end) ? *(const uint2*)(edges + i + 6 * G) : zz;
        float4 a0 = h4_to_f4(rates_in[p0.x & 0xFFFFu]);
        float4 a1 = h4_to_f4(rates_in[p0.y & 0xFFFFu]);
        float4 a2 = h4_to_f4(rates_in[p1.x & 0xFFFFu]);
        float4 a3 = h4_to_f4(rates_in[p1.y & 0xFFFFu]);
        float w0 = rec_w(p0.x), w1 = rec_w(p0.y), w2 = rec_w(p1.x), w3 = rec_w(p1.y);
        acc.x = fmaf(a0.x, w0, acc.x); acc.y = fmaf(a0.y, w0, acc.y);
        acc.z = fmaf(a0.z, w0, acc.z); acc.w = fmaf(a0.w, w0, acc.w);
        acc.x = fmaf(a1.x, w1, acc.x); acc.y = fmaf(a1.y, w1, acc.y);
        acc.z = fmaf(a1.z, w1, acc.z); acc.w = fmaf(a1.w, w1, acc.w);
        acc.x = fmaf(a2.x, w2, acc.x); acc.y = fmaf(a2.y, w2, acc.y);
        acc.z = fmaf(a2.z, w2, acc.z); acc.w = fmaf(a2.w, w2, acc.w);
        acc.x = fmaf(a3.x, w3, acc.x); acc.y = fmaf(a3.y, w3, acc.y);
        acc.z = fmaf(a3.z, w3, acc.z); acc.w = fmaf(a3.w, w3, acc.w);
        p0 = q0; p1 = q1;
        i += 4 * G;
    }

#pragma unroll
    for (int m = 1; m < G; m <<= 1) {
        acc.x += __shfl_xor(acc.x, m, 64);
        acc.y += __shfl_xor(acc.y, m, 64);
        acc.z += __shfl_xor(acc.z, m, 64);
        acc.w += __shfl_xor(acc.w, m, 64);
    }

    if (lane < 4) {   // lane l handles batch element l
        float sum = (lane == 0) ? acc.x : (lane == 1) ? acc.y
                  : (lane == 2) ? acc.z : acc.w;
        float2 abv = ab[node];
        const int TN = T_STEPS * N_NODES;
        int vi = lane * N_NODES + node;
        int oi = lane * TN + t * N_NODES + node;
        float vv = v[vi];
        float xv = __builtin_nontemporal_load(x + oi);
        float vn = vv + abv.x * (abv.y + sum + xv - vv);
        v[vi] = vn;
        float r = fmaxf(vn, 0.f);
        rates_out[node * 4 + lane] = __float2half(r);
        __builtin_nontemporal_store(r, out + oi);
    }
}

// ---------------- launch ----------------

extern "C" void kernel_launch(void* const* d_in, const int* in_sizes, int n_in,
                              void* d_out, int out_size, void* d_ws, size_t ws_size,
                              hipStream_t stream) {
    const float* x            = (const float*)d_in[0];
    const float* bias         = (const float*)d_in[1];
    const float* time_const   = (const float*)d_in[2];
    const float* sign         = (const float*)d_in[3];
    const float* syn_count    = (const float*)d_in[4];
    const float* syn_strength = (const float*)d_in[5];
    const int*   src_idx      = (const int*)d_in[6];
    const int*   tgt_idx      = (const int*)d_in[7];
    float* out = (float*)d_out;

    char* ws = (char*)d_ws;
    size_t off = 0;
    auto alloc = [&](size_t bytes) -> void* {
        void* p = ws + off;
        off = (off + bytes + 255) & ~(size_t)255;
        return p;
    };
    float*  v       = (float*) alloc((size_t)N_NODES * 4 * 4);   // [4][N] SoA
    uint2*  rates_a = (uint2*) alloc((size_t)N_NODES * 8);       // half4 per node
    uint2*  rates_b = (uint2*) alloc((size_t)N_NODES * 8);
    float2* ab      = (float2*)alloc((size_t)N_NODES * 8);
    int*    offsets = (int*)   alloc((size_t)N_NODES * 4);
    int*    ends    = (int*)   alloc((size_t)N_NODES * 4);
    int*    bucket_count = (int*)alloc((size_t)NB * 4);
    unsigned int* edges = (unsigned int*)alloc((size_t)NB * CAP2 * 4); // 7.3 MB
    unsigned long long* rec_buf =
        (unsigned long long*)alloc((size_t)NB * CAP * 8);   // 14.2 MB

    int nb_tiles = (N_EDGES + TILE - 1) / TILE;

    zero_kernel<<<1, 256, 0, stream>>>(bucket_count);
    bucket_kernel<<<nb_tiles, 256, 0, stream>>>(src_idx, tgt_idx, sign, syn_count,
                                                syn_strength, bucket_count, rec_buf);
    sort_kernel<<<NB, 256, 0, stream>>>(bucket_count, rec_buf, bias, time_const,
                                        edges, offsets, ends, ab, v, rates_a);

    int nblk = (N_NODES + (256 / G) - 1) / (256 / G);
    for (int t = 0; t < T_STEPS; ++t) {
        const uint2* rin  = (t & 1) ? rates_b : rates_a;
        __half*      rout = (__half*)((t & 1) ? rates_a : rates_b);
        step_kernel<<<nblk, 256, 0, stream>>>(rin, rout, v, ab,
                                              offsets, ends, edges, x, out, t, nblk);
    }
}